// Round 6
// baseline (170.434 us; speedup 1.0000x reference)
//
#include <hip/hip_runtime.h>
#include <stdint.h>

#define Nn 4
#define Cc 64
#define LL 4096   // H*W
#define KK 256    // feature dim: 64 channels * 4 causal taps

typedef _Float16 half8 __attribute__((ext_vector_type(8)));
typedef float f32x16 __attribute__((ext_vector_type(16)));
typedef float f4a __attribute__((ext_vector_type(4), aligned(4)));

__device__ __forceinline__ unsigned f2ord(float f) {
    unsigned u = __float_as_uint(f);
    return u ^ ((u & 0x80000000u) ? 0xFFFFFFFFu : 0x80000000u);
}
__device__ __forceinline__ float ord2f(unsigned o) {
    unsigned u = (o & 0x80000000u) ? (o ^ 0x80000000u) : ~o;
    return __uint_as_float(u);
}
__device__ __forceinline__ unsigned short h2u(_Float16 h) {
    union { _Float16 f; unsigned short u; } x; x.f = h; return x.u;
}

// Kernel 1: per-(n,y) block, y_hat rows (y-1,y) staged in LDS (coalesced).
// Emits pre-scaled split-fp16: Vh' = 2048*fp16(v), Vl = fp16((v-fp16(v))*2048).
// Also zeroes its slice of `best` (replaces the memset dispatch).
__global__ __launch_bounds__(256) void build_v(const float* __restrict__ yhat,
                                               unsigned short* __restrict__ VhT,
                                               unsigned short* __restrict__ VlT,
                                               unsigned long long* __restrict__ best) {
    __shared__ float P[4096];   // prev row, [ch][x]
    __shared__ float Cr[4096];  // cur row
    int b = blockIdx.x;
    int n = b >> 6, y = b & 63;
    int tid = threadIdx.x;
    if (tid < 64) best[(size_t)n * LL + y * 64 + tid] = 0ull;

    const float* src = yhat + (size_t)n * (Cc * LL);
#pragma unroll
    for (int k = 0; k < 8; ++k) {
        int f4i = tid + 256 * k;          // 0..2047
        int plane = f4i >> 10;            // 0=prev 1=cur
        int rem = f4i & 1023;
        int ch = rem >> 4, xq = rem & 15;
        if (plane == 0) {
            float4 v = make_float4(0.f, 0.f, 0.f, 0.f);
            if (y > 0) v = *(const float4*)(src + (size_t)ch * LL + (y - 1) * 64 + xq * 4);
            *(float4*)&P[ch * 64 + xq * 4] = v;
        } else {
            float4 v = *(const float4*)(src + (size_t)ch * LL + y * 64 + xq * 4);
            *(float4*)&Cr[ch * 64 + xq * 4] = v;
        }
    }
    __syncthreads();

    int cq = tid & 3, x = tid >> 2;       // 4 lanes share one x (16 ch each)
    float sumsq = 0.f;
#pragma unroll
    for (int ci = 0; ci < 16; ++ci) {
        int ch = cq * 16 + ci;
        const float* pp = &P[ch * 64];
        const float* pc = &Cr[ch * 64];
        float t0 = (x > 0)  ? pp[x - 1] : 0.f;
        float t1 = pp[x];
        float t2 = (x < 63) ? pp[x + 1] : 0.f;
        float t3 = (x > 0)  ? pc[x - 1] : 0.f;
        sumsq += t0 * t0 + t1 * t1 + t2 * t2 + t3 * t3;
    }
    sumsq += __shfl_xor(sumsq, 1, 64);
    sumsq += __shfl_xor(sumsq, 2, 64);
    float inv = 1.f / fmaxf(sqrtf(sumsq), 1e-12f);

    size_t nl = (size_t)n * LL + y * 64 + x;
    unsigned short* dh = VhT + nl * KK + cq * 64;
    unsigned short* dl = VlT + nl * KK + cq * 64;
#pragma unroll
    for (int ci = 0; ci < 16; ++ci) {
        int ch = cq * 16 + ci;
        const float* pp = &P[ch * 64];
        const float* pc = &Cr[ch * 64];
        float t[4];
        t[0] = (x > 0)  ? pp[x - 1] : 0.f;
        t[1] = pp[x];
        t[2] = (x < 63) ? pp[x + 1] : 0.f;
        t[3] = (x > 0)  ? pc[x - 1] : 0.f;
        ushort4 hv, lv;
        unsigned short* ph = &hv.x;
        unsigned short* pl = &lv.x;
#pragma unroll
        for (int tp = 0; tp < 4; ++tp) {
            float v = t[tp] * inv;
            _Float16 h = (fabsf(v) < 6.1035e-5f) ? (_Float16)0 : (_Float16)v;
            _Float16 lo = (_Float16)((v - (float)h) * 2048.0f);
            ph[tp] = h2u(h * (_Float16)2048.0f);
            pl[tp] = h2u(lo);
        }
        *(ushort4*)(dh + ci * 4) = hv;
        *(ushort4*)(dl + ci * 4) = lv;
    }
}

// Kernel 2: 128x256 block tiles, 4 waves of 64x128 (acc 2x4 of 32x32).
// Staging: global_load_lds width=16, unpadded 64B rows, XOR chunk swizzle
// c_lds = c_g ^ ((row>>1)&3) (conflict-free reads AND stores).
// LDS halves: Ah[0,4096) Al[4096,8192) Bh[8192,16384) Bl[16384,24576) = 48 KB.
__global__ __launch_bounds__(256, 2) void simmax(const unsigned short* __restrict__ Vh,
                                                 const unsigned short* __restrict__ Vl,
                                                 unsigned long long* __restrict__ best) {
    __shared__ __align__(16) unsigned short S[24576];

    int bx = blockIdx.x;                // 0..1087
    int xcd = bx & 7, idx = bx >> 3;    // XCD-pin: each XCD owns half of one batch
    int n = xcd >> 1;
    int t = (xcd & 1) * 136 + idx;      // 0..271
    // t = J*(J+1) + i, i in [0, 2J+2): J = col-block (256 wide), i = row-block (128)
    int J = (int)((sqrtf(4.f * (float)t + 1.f) - 1.f) * 0.5f);
    while ((J + 1) * (J + 2) <= t) ++J;
    while (J * (J + 1) > t) --J;
    int i = t - J * (J + 1);
    int l0 = i * 128, m0 = J * 256;

    const unsigned short* VhB = Vh + (size_t)n * (LL * KK);
    const unsigned short* VlB = Vl + (size_t)n * (LL * KK);

    int tid = threadIdx.x;
    int w = tid >> 6, lane = tid & 63;
    int r5 = lane & 31, h5 = lane >> 5;
    int rw = (w & 1) * 64;      // wave rows (l) 0/64
    int cw = (w >> 1) * 128;    // wave cols (m) 0/128
    bool skip = (l0 + rw) > (m0 + cw + 127);   // wave fully l>m

    f32x16 acc[2][4];
#pragma unroll
    for (int r = 0; r < 2; ++r)
#pragma unroll
        for (int c = 0; c < 4; ++c) acc[r][c] = (f32x16)0.f;

    int rl = lane >> 2, cl = lane & 3;  // staging: 16 rows x 4 chunks per call
    int arow0 = rw + r5, arow1 = rw + 32 + r5;
    int sA0 = (arow0 >> 1) & 3, sA1 = (arow1 >> 1) & 3;
    int brow[4], sB[4];
#pragma unroll
    for (int ct = 0; ct < 4; ++ct) {
        brow[ct] = cw + ct * 32 + r5;
        sB[ct] = (brow[ct] >> 1) & 3;
    }

    for (int k0 = 0; k0 < KK; k0 += 32) {
#pragma unroll
        for (int qq = 0; qq < 12; ++qq) {
            int q = w * 12 + qq;        // 48 calls: Ah 0-7, Al 8-15, Bh 16-31, Bl 32-47
            int buf = (q < 8) ? 0 : (q < 16) ? 1 : (q < 32) ? 2 : 3;
            int rg = q - ((buf == 0) ? 0 : (buf == 1) ? 8 : (buf == 2) ? 16 : 32);
            const unsigned short* srcb = (buf & 1) ? VlB : VhB;
            int tile0 = (buf < 2) ? l0 : m0;
            int row_local = rg * 16 + rl;
            int cg = cl ^ ((row_local >> 1) & 3);
            const unsigned short* gp = srcb + (size_t)(tile0 + row_local) * KK + k0 + cg * 8;
            int hb = ((buf == 0) ? 0 : (buf == 1) ? 4096 : (buf == 2) ? 8192 : 16384) + rg * 512;
            __builtin_amdgcn_global_load_lds(
                (const __attribute__((address_space(1))) unsigned int*)(uintptr_t)gp,
                (__attribute__((address_space(3))) unsigned int*)(uintptr_t)(&S[hb]),
                16, 0, 0);
        }
        __syncthreads();
        if (!skip) {
#pragma unroll
            for (int kc = 0; kc < 2; ++kc) {
                int c0 = kc * 2 + h5;
                half8 fah0 = *(half8*)&S[arow0 * 32 + ((c0 ^ sA0) * 8)];
                half8 fah1 = *(half8*)&S[arow1 * 32 + ((c0 ^ sA1) * 8)];
                half8 fal0 = *(half8*)&S[4096 + arow0 * 32 + ((c0 ^ sA0) * 8)];
                half8 fal1 = *(half8*)&S[4096 + arow1 * 32 + ((c0 ^ sA1) * 8)];
                half8 fbh[4], fbl[4];
#pragma unroll
                for (int ct = 0; ct < 4; ++ct) {
                    fbh[ct] = *(half8*)&S[8192 + brow[ct] * 32 + ((c0 ^ sB[ct]) * 8)];
                    fbl[ct] = *(half8*)&S[16384 + brow[ct] * 32 + ((c0 ^ sB[ct]) * 8)];
                }
#pragma unroll
                for (int ct = 0; ct < 4; ++ct) {
                    acc[0][ct] = __builtin_amdgcn_mfma_f32_32x32x16_f16(fal0, fbh[ct], acc[0][ct], 0, 0, 0);
                    acc[1][ct] = __builtin_amdgcn_mfma_f32_32x32x16_f16(fal1, fbh[ct], acc[1][ct], 0, 0, 0);
                }
#pragma unroll
                for (int ct = 0; ct < 4; ++ct) {
                    acc[0][ct] = __builtin_amdgcn_mfma_f32_32x32x16_f16(fah0, fbl[ct], acc[0][ct], 0, 0, 0);
                    acc[1][ct] = __builtin_amdgcn_mfma_f32_32x32x16_f16(fah1, fbl[ct], acc[1][ct], 0, 0, 0);
                }
#pragma unroll
                for (int ct = 0; ct < 4; ++ct) {
                    acc[0][ct] = __builtin_amdgcn_mfma_f32_32x32x16_f16(fah0, fbh[ct], acc[0][ct], 0, 0, 0);
                    acc[1][ct] = __builtin_amdgcn_mfma_f32_32x32x16_f16(fah1, fbh[ct], acc[1][ct], 0, 0, 0);
                }
            }
        }
        __syncthreads();
    }

    if (skip) return;
    unsigned long long* bb = best + (size_t)n * LL;
    const float s = 1.f / 4194304.f;   // 2^-22
#pragma unroll
    for (int ct = 0; ct < 4; ++ct) {
        int m = m0 + cw + ct * 32 + r5;
        unsigned long long key = 0ull;
#pragma unroll
        for (int rt = 0; rt < 2; ++rt)
#pragma unroll
            for (int g = 0; g < 16; ++g) {
                int l = l0 + rw + rt * 32 + (g & 3) + 8 * (g >> 2) + 4 * h5;
                if (l < m) {
                    float v = acc[rt][ct][g] * s;
                    unsigned long long k2 =
                        ((unsigned long long)f2ord(v) << 32) |
                        (unsigned long long)(0xFFFFFFFFu - (unsigned)l);
                    key = (k2 > key) ? k2 : key;
                }
            }
        unsigned long long o = __shfl_xor(key, 32, 64);
        key = (o > key) ? o : key;
        if (h5 == 0 && key != 0ull) atomicMax(bb + m, key);
    }
}

// Kernel 3: unpack best, write S, U, ref_unfold, arg (float values), m==0 overrides.
__global__ __launch_bounds__(256) void writeout(const float* __restrict__ yhat,
                                                const float* __restrict__ yprob,
                                                const unsigned long long* __restrict__ best,
                                                float* __restrict__ out) {
    int bx = blockIdx.x;          // n*256 + mb*4 + fc
    int n = bx >> 8;
    int mb = (bx >> 2) & 63;
    int fc = bx & 3;
    int tid = threadIdx.x;
    int mm = tid & 63;
    int fs = tid >> 6;
    int m = mb * 64 + mm;

    unsigned long long key = best[(size_t)n * LL + m];
    unsigned l = 0xFFFFFFFFu - (unsigned)(key & 0xFFFFFFFFull);
    float val = ord2f((unsigned)(key >> 32));
    bool zero = (m == 0);
    if (zero) l = 0;
    int ly = (int)(l >> 6), lx = (int)(l & 63);

    float* Sout = out;                       // [4,1,64,64]
    float* Uout = out + 16384;               // [4,1,64,64]
    float* Rout = out + 32768;               // [4,576,4096]
    float* Aout = out + 9469952;             // [4,4096] as float values

    if (fc == 0 && fs == 0) {
        float S = zero ? 1e-8f : fminf(fmaxf(val, 1e-8f), 1.0f);
        float U = zero ? 1e-8f : fminf(fmaxf(yprob[(size_t)n * LL + l], 1e-8f), 1.0f);
        Sout[(size_t)n * LL + m] = S;
        Uout[(size_t)n * LL + m] = U;
        Aout[(size_t)n * LL + m] = zero ? -1.0f : (float)l;
    }

    const float* src = yhat + (size_t)n * (Cc * LL);
    float* dst = Rout + (size_t)n * (576 * LL) + m;
    bool fast = (!zero) && (lx >= 1) && (lx <= 61);
#pragma unroll
    for (int cc = 0; cc < 4; ++cc) {
        int c = fc * 16 + fs * 4 + cc;
        const float* plane = src + (size_t)c * LL;
#pragma unroll
        for (int r3 = 0; r3 < 3; ++r3) {
            int yy = ly + r3 - 1;
            bool rowok = (!zero) && (yy >= 0) && (yy < 64);
            float t0 = 0.f, t1 = 0.f, t2 = 0.f;
            if (rowok) {
                if (fast) {
                    f4a v = *(const f4a*)(plane + yy * 64 + lx - 1);
                    t0 = v.x; t1 = v.y; t2 = v.z;
                } else {
                    if (lx > 0)  t0 = plane[yy * 64 + lx - 1];
                    t1 = plane[yy * 64 + lx];
                    if (lx < 63) t2 = plane[yy * 64 + lx + 1];
                }
            }
            size_t f = (size_t)(c * 9 + r3 * 3) * LL;
            __builtin_nontemporal_store(t0, dst + f);
            __builtin_nontemporal_store(t1, dst + f + LL);
            __builtin_nontemporal_store(t2, dst + f + 2 * (size_t)LL);
        }
    }
}

extern "C" void kernel_launch(void* const* d_in, const int* in_sizes, int n_in,
                              void* d_out, int out_size, void* d_ws, size_t ws_size,
                              hipStream_t stream) {
    const float* yhat  = (const float*)d_in[0];
    const float* yprob = (const float*)d_in[1];
    float* out = (float*)d_out;

    unsigned short* VhT = (unsigned short*)d_ws;                       // 8 MiB
    unsigned short* VlT = (unsigned short*)((char*)d_ws + 8388608);    // 8 MiB
    unsigned long long* best =
        (unsigned long long*)((char*)d_ws + 16777216);                 // 128 KiB

    build_v<<<256, 256, 0, stream>>>(yhat, VhT, VlT, best);
    simmax<<<Nn * 272, 256, 0, stream>>>(VhT, VlT, best);
    writeout<<<Nn * 64 * 4, 256, 0, stream>>>(yhat, yprob, best, out);
}

// Round 7
// 156.480 us; speedup vs baseline: 1.0892x; 1.0892x over previous
//
#include <hip/hip_runtime.h>
#include <stdint.h>

#define Nn 4
#define Cc 64
#define LL 4096   // H*W
#define KK 256    // feature dim: 64 channels * 4 causal taps
#define TRI2 528  // 32*33/2 triangular 128x128 tile pairs per batch
#define PAD_H 40  // LDS row stride in halves (32 data + 8 pad = 80 B, 16B-aligned)

typedef _Float16 half8 __attribute__((ext_vector_type(8)));
typedef float f32x16 __attribute__((ext_vector_type(16)));
typedef float f4a __attribute__((ext_vector_type(4), aligned(4)));

__device__ __forceinline__ unsigned f2ord(float f) {
    unsigned u = __float_as_uint(f);
    return u ^ ((u & 0x80000000u) ? 0xFFFFFFFFu : 0x80000000u);
}
__device__ __forceinline__ float ord2f(unsigned o) {
    unsigned u = (o & 0x80000000u) ? (o ^ 0x80000000u) : ~o;
    return __uint_as_float(u);
}
__device__ __forceinline__ unsigned short h2u(_Float16 h) {
    union { _Float16 f; unsigned short u; } x; x.f = h; return x.u;
}

// Kernel 1: normalized masked context vectors, split fp16 hi/lo, both pre-scaled:
//   Vh' = 2048*fp16(v)  (exact pow2),  Vl = fp16((v - fp16(v)) * 2048)
// Layout: [n][l][k], k = c*4+tap contiguous. 16 lanes cooperate per l (4 ch each).
// XCD-pinned (n = (blk&7)>>1) and zeroes its slice of `best` (replaces memset).
__global__ __launch_bounds__(256) void build_v(const float* __restrict__ yhat,
                                               unsigned short* __restrict__ VhT,
                                               unsigned short* __restrict__ VlT,
                                               unsigned long long* __restrict__ best) {
    int blk = blockIdx.x;                       // 0..1023
    int xcd = blk & 7;
    int n = xcd >> 1;
    int i64 = (blk >> 3) + (xcd & 1) * 128;     // 0..255; block covers l = i64*16 ..+16
    int tid = threadIdx.x;
    if (tid < 16) best[(size_t)n * LL + i64 * 16 + tid] = 0ull;

    int cg = tid & 15;           // channel group 0..15 (4 channels each)
    int l = i64 * 16 + (tid >> 4);
    int y = l >> 6, x = l & 63;
    const float* src = yhat + (size_t)n * (Cc * LL);

    float vals[16];
    float sumsq = 0.f;
#pragma unroll
    for (int ci = 0; ci < 4; ++ci) {
        const float* p = src + (cg * 4 + ci) * LL;
        float t0 = (y > 0 && x > 0)  ? p[l - 65] : 0.f;
        float t1 = (y > 0)           ? p[l - 64] : 0.f;
        float t2 = (y > 0 && x < 63) ? p[l - 63] : 0.f;
        float t3 = (x > 0)           ? p[l - 1]  : 0.f;
        vals[ci * 4 + 0] = t0; vals[ci * 4 + 1] = t1;
        vals[ci * 4 + 2] = t2; vals[ci * 4 + 3] = t3;
        sumsq += t0 * t0 + t1 * t1 + t2 * t2 + t3 * t3;
    }
    sumsq += __shfl_xor(sumsq, 1, 64);
    sumsq += __shfl_xor(sumsq, 2, 64);
    sumsq += __shfl_xor(sumsq, 4, 64);
    sumsq += __shfl_xor(sumsq, 8, 64);
    float inv = 1.f / fmaxf(sqrtf(sumsq), 1e-12f);

    size_t nl = (size_t)n * LL + l;
    unsigned short* dh = VhT + nl * KK + cg * 16;
    unsigned short* dl = VlT + nl * KK + cg * 16;
#pragma unroll
    for (int ci = 0; ci < 4; ++ci) {
        ushort4 hv, lv;
        unsigned short* ph = &hv.x;
        unsigned short* pl = &lv.x;
#pragma unroll
        for (int tp = 0; tp < 4; ++tp) {
            float v = vals[ci * 4 + tp] * inv;
            _Float16 h = (fabsf(v) < 6.1035e-5f) ? (_Float16)0 : (_Float16)v;
            _Float16 lo = (_Float16)((v - (float)h) * 2048.0f);
            ph[tp] = h2u(h * (_Float16)2048.0f);   // exact pow2 scale
            pl[tp] = h2u(lo);
        }
        *(ushort4*)(dh + ci * 4) = hv;
        *(ushort4*)(dl + ci * 4) = lv;
    }
}

// Kernel 2 (R5-proven, 69.3us): triangular 128x128-tiled similarity-max via
// split-fp16 32x32x16 MFMA. acc = Vh1'Vh2' + Vh1'Vl2 + Vl1Vh2' = 2^22 * v1.v2.
// 32x32x16 layouts: A/B row(col)=lane&31, k=(lane>>5)*8+j;
// C/D: col=lane&31, row=(reg&3)+8*(reg>>2)+4*(lane>>5).
__global__ __launch_bounds__(256) void simmax(const unsigned short* __restrict__ Vh,
                                              const unsigned short* __restrict__ Vl,
                                              unsigned long long* __restrict__ best) {
    __shared__ __align__(16) unsigned short Ah[128 * PAD_H];
    __shared__ __align__(16) unsigned short Al[128 * PAD_H];
    __shared__ __align__(16) unsigned short Bh[128 * PAD_H];
    __shared__ __align__(16) unsigned short Bl[128 * PAD_H];

    int bx = blockIdx.x;              // 0..2111
    int xcd = bx & 7, idx = bx >> 3;  // XCD-pin: each XCD owns half of one batch
    int n = xcd >> 1;
    int t = (xcd & 1) * 264 + idx;    // 0..527
    int j = (int)((sqrtf(8.f * (float)t + 1.f) - 1.f) * 0.5f);
    while ((j + 1) * (j + 2) / 2 <= t) ++j;
    while (j * (j + 1) / 2 > t) --j;
    int i = t - j * (j + 1) / 2;
    int l0 = i * 128, m0 = j * 128;

    const unsigned short* VhB = Vh + (size_t)n * (LL * KK);
    const unsigned short* VlB = Vl + (size_t)n * (LL * KK);

    int tid = threadIdx.x;
    int w = tid >> 6, lane = tid & 63;
    int r5 = lane & 31, h5 = lane >> 5;
    int rw = (w & 1) * 64;    // wave rows (l)
    int cw = (w >> 1) * 64;   // wave cols (m)
    bool skip = (i == j) && (rw == 64) && (cw == 0);  // fully l>m

    f32x16 acc[2][2];
#pragma unroll
    for (int r = 0; r < 2; ++r)
#pragma unroll
        for (int c = 0; c < 2; ++c) acc[r][c] = (f32x16)0.f;

    int srow = tid >> 2;          // 0..63
    int sh = (tid & 3) * 8;       // 0,8,16,24

    for (int k0 = 0; k0 < KK; k0 += 32) {
        const size_t ra = (size_t)(l0 + srow) * KK + k0 + sh;
        const size_t rb = (size_t)(l0 + 64 + srow) * KK + k0 + sh;
        const size_t rc = (size_t)(m0 + srow) * KK + k0 + sh;
        const size_t rd = (size_t)(m0 + 64 + srow) * KK + k0 + sh;
        uint4 ah0 = *(const uint4*)(VhB + ra);
        uint4 ah1 = *(const uint4*)(VhB + rb);
        uint4 al0 = *(const uint4*)(VlB + ra);
        uint4 al1 = *(const uint4*)(VlB + rb);
        uint4 bh0 = *(const uint4*)(VhB + rc);
        uint4 bh1 = *(const uint4*)(VhB + rd);
        uint4 bl0 = *(const uint4*)(VlB + rc);
        uint4 bl1 = *(const uint4*)(VlB + rd);
        __syncthreads();
        *(uint4*)&Ah[srow * PAD_H + sh]        = ah0;
        *(uint4*)&Ah[(64 + srow) * PAD_H + sh] = ah1;
        *(uint4*)&Al[srow * PAD_H + sh]        = al0;
        *(uint4*)&Al[(64 + srow) * PAD_H + sh] = al1;
        *(uint4*)&Bh[srow * PAD_H + sh]        = bh0;
        *(uint4*)&Bh[(64 + srow) * PAD_H + sh] = bh1;
        *(uint4*)&Bl[srow * PAD_H + sh]        = bl0;
        *(uint4*)&Bl[(64 + srow) * PAD_H + sh] = bl1;
        __syncthreads();
        if (!skip) {
            half8 fah[2][2], fal[2][2], fbh[2][2], fbl[2][2];
#pragma unroll
            for (int r = 0; r < 2; ++r)
#pragma unroll
                for (int kc = 0; kc < 2; ++kc) {
                    int ao = (rw + r * 32 + r5) * PAD_H + kc * 16 + h5 * 8;
                    int bo = (cw + r * 32 + r5) * PAD_H + kc * 16 + h5 * 8;
                    fah[r][kc] = *(half8*)&Ah[ao];
                    fal[r][kc] = *(half8*)&Al[ao];
                    fbh[r][kc] = *(half8*)&Bh[bo];
                    fbl[r][kc] = *(half8*)&Bl[bo];
                }
#pragma unroll
            for (int kc = 0; kc < 2; ++kc)
#pragma unroll
                for (int r = 0; r < 2; ++r)
#pragma unroll
                    for (int c = 0; c < 2; ++c)
                        acc[r][c] = __builtin_amdgcn_mfma_f32_32x32x16_f16(fal[r][kc], fbh[c][kc], acc[r][c], 0, 0, 0);
#pragma unroll
            for (int kc = 0; kc < 2; ++kc)
#pragma unroll
                for (int r = 0; r < 2; ++r)
#pragma unroll
                    for (int c = 0; c < 2; ++c)
                        acc[r][c] = __builtin_amdgcn_mfma_f32_32x32x16_f16(fah[r][kc], fbl[c][kc], acc[r][c], 0, 0, 0);
#pragma unroll
            for (int kc = 0; kc < 2; ++kc)
#pragma unroll
                for (int r = 0; r < 2; ++r)
#pragma unroll
                    for (int c = 0; c < 2; ++c)
                        acc[r][c] = __builtin_amdgcn_mfma_f32_32x32x16_f16(fah[r][kc], fbh[c][kc], acc[r][c], 0, 0, 0);
        }
    }

    if (skip) return;
    unsigned long long* bb = best + (size_t)n * LL;
    const float s = 1.f / 4194304.f;   // 2^-22
#pragma unroll
    for (int c = 0; c < 2; ++c) {
        int m = m0 + cw + c * 32 + r5;
        unsigned long long key = 0ull;
#pragma unroll
        for (int r = 0; r < 2; ++r)
#pragma unroll
            for (int g = 0; g < 16; ++g) {
                int l = l0 + rw + r * 32 + (g & 3) + 8 * (g >> 2) + 4 * h5;
                if (l < m) {
                    float v = acc[r][c][g] * s;
                    unsigned long long k2 =
                        ((unsigned long long)f2ord(v) << 32) |
                        (unsigned long long)(0xFFFFFFFFu - (unsigned)l);
                    key = (k2 > key) ? k2 : key;
                }
            }
        unsigned long long o = __shfl_xor(key, 32, 64);
        key = (o > key) ? o : key;
        if (h5 == 0 && key != 0ull) atomicMax(bb + m, key);
    }
}

// Kernel 3: unpack best, write S, U, ref_unfold, arg (float values), m==0 overrides.
// 4096 blocks (16 channel-groups of 4) for TLP; XCD-pinned per batch.
// Each thread: 1 channel x 3 rows (3 gathers + 9 stores).
__global__ __launch_bounds__(256) void writeout(const float* __restrict__ yhat,
                                                const float* __restrict__ yprob,
                                                const unsigned long long* __restrict__ best,
                                                float* __restrict__ out) {
    int blk = blockIdx.x;                     // 0..4095
    int xcd = blk & 7;
    int n = xcd >> 1;
    int idx = (blk >> 3) + (xcd & 1) * 512;   // 0..1023
    int mb = idx >> 4;                        // 0..63
    int fc = idx & 15;                        // channel group of 4
    int tid = threadIdx.x;
    int mm = tid & 63;
    int fs = tid >> 6;                        // 0..3
    int c = fc * 4 + fs;
    int m = mb * 64 + mm;

    unsigned long long key = best[(size_t)n * LL + m];
    unsigned l = 0xFFFFFFFFu - (unsigned)(key & 0xFFFFFFFFull);
    float val = ord2f((unsigned)(key >> 32));
    bool zero = (m == 0);
    if (zero) l = 0;
    int ly = (int)(l >> 6), lx = (int)(l & 63);

    float* Sout = out;                       // [4,1,64,64]
    float* Uout = out + 16384;               // [4,1,64,64]
    float* Rout = out + 32768;               // [4,576,4096]
    float* Aout = out + 9469952;             // [4,4096] as float values

    if (fc == 0 && fs == 0) {
        float S = zero ? 1e-8f : fminf(fmaxf(val, 1e-8f), 1.0f);
        float U = zero ? 1e-8f : fminf(fmaxf(yprob[(size_t)n * LL + l], 1e-8f), 1.0f);
        Sout[(size_t)n * LL + m] = S;
        Uout[(size_t)n * LL + m] = U;
        Aout[(size_t)n * LL + m] = zero ? -1.0f : (float)l;
    }

    const float* src = yhat + (size_t)n * (Cc * LL);
    const float* plane = src + (size_t)c * LL;
    float* dst = Rout + (size_t)n * (576 * LL) + m;
    bool fast = (!zero) && (lx >= 1) && (lx <= 61);
#pragma unroll
    for (int r3 = 0; r3 < 3; ++r3) {
        int yy = ly + r3 - 1;
        bool rowok = (!zero) && (yy >= 0) && (yy < 64);
        float t0 = 0.f, t1 = 0.f, t2 = 0.f;
        if (rowok) {
            if (fast) {
                f4a v = *(const f4a*)(plane + yy * 64 + lx - 1);
                t0 = v.x; t1 = v.y; t2 = v.z;
            } else {
                if (lx > 0)  t0 = plane[yy * 64 + lx - 1];
                t1 = plane[yy * 64 + lx];
                if (lx < 63) t2 = plane[yy * 64 + lx + 1];
            }
        }
        size_t f = (size_t)(c * 9 + r3 * 3) * LL;
        __builtin_nontemporal_store(t0, dst + f);
        __builtin_nontemporal_store(t1, dst + f + LL);
        __builtin_nontemporal_store(t2, dst + f + 2 * (size_t)LL);
    }
}

extern "C" void kernel_launch(void* const* d_in, const int* in_sizes, int n_in,
                              void* d_out, int out_size, void* d_ws, size_t ws_size,
                              hipStream_t stream) {
    const float* yhat  = (const float*)d_in[0];
    const float* yprob = (const float*)d_in[1];
    float* out = (float*)d_out;

    unsigned short* VhT = (unsigned short*)d_ws;                       // 8 MiB
    unsigned short* VlT = (unsigned short*)((char*)d_ws + 8388608);    // 8 MiB
    unsigned long long* best =
        (unsigned long long*)((char*)d_ws + 16777216);                 // 128 KiB

    build_v<<<1024, 256, 0, stream>>>(yhat, VhT, VlT, best);
    simmax<<<Nn * TRI2, 256, 0, stream>>>(VhT, VlT, best);
    writeout<<<4096, 256, 0, stream>>>(yhat, yprob, best, out);
}

// Round 8
// 156.088 us; speedup vs baseline: 1.0919x; 1.0025x over previous
//
#include <hip/hip_runtime.h>
#include <stdint.h>

#define Nn 4
#define Cc 64
#define LL 4096   // H*W
#define KK 256    // feature dim: 64 channels * 4 causal taps
#define TRI2 528  // 32*33/2 triangular 128x128 tile pairs per batch

typedef _Float16 half8 __attribute__((ext_vector_type(8)));
typedef float f32x16 __attribute__((ext_vector_type(16)));
typedef float f4a __attribute__((ext_vector_type(4), aligned(4)));

__device__ __forceinline__ unsigned f2ord(float f) {
    unsigned u = __float_as_uint(f);
    return u ^ ((u & 0x80000000u) ? 0xFFFFFFFFu : 0x80000000u);
}
__device__ __forceinline__ float ord2f(unsigned o) {
    unsigned u = (o & 0x80000000u) ? (o ^ 0x80000000u) : ~o;
    return __uint_as_float(u);
}
__device__ __forceinline__ unsigned short h2u(_Float16 h) {
    union { _Float16 f; unsigned short u; } x; x.f = h; return x.u;
}

// Kernel 1: normalized masked context vectors, split fp16 hi/lo, both pre-scaled:
//   Vh' = 2048*fp16(v)  (exact pow2),  Vl = fp16((v - fp16(v)) * 2048)
// Layout: [n][l][k], k = c*4+tap contiguous. 16 lanes cooperate per l (4 ch each).
// XCD-pinned and zeroes its slice of `best` (replaces memset dispatch).
__global__ __launch_bounds__(256) void build_v(const float* __restrict__ yhat,
                                               unsigned short* __restrict__ VhT,
                                               unsigned short* __restrict__ VlT,
                                               unsigned long long* __restrict__ best) {
    int blk = blockIdx.x;                       // 0..1023
    int xcd = blk & 7;
    int n = xcd >> 1;
    int i64 = (blk >> 3) + (xcd & 1) * 128;     // 0..255; block covers l = i64*16 ..+16
    int tid = threadIdx.x;
    if (tid < 16) best[(size_t)n * LL + i64 * 16 + tid] = 0ull;

    int cg = tid & 15;           // channel group 0..15 (4 channels each)
    int l = i64 * 16 + (tid >> 4);
    int y = l >> 6, x = l & 63;
    const float* src = yhat + (size_t)n * (Cc * LL);

    float vals[16];
    float sumsq = 0.f;
#pragma unroll
    for (int ci = 0; ci < 4; ++ci) {
        const float* p = src + (cg * 4 + ci) * LL;
        float t0 = (y > 0 && x > 0)  ? p[l - 65] : 0.f;
        float t1 = (y > 0)           ? p[l - 64] : 0.f;
        float t2 = (y > 0 && x < 63) ? p[l - 63] : 0.f;
        float t3 = (x > 0)           ? p[l - 1]  : 0.f;
        vals[ci * 4 + 0] = t0; vals[ci * 4 + 1] = t1;
        vals[ci * 4 + 2] = t2; vals[ci * 4 + 3] = t3;
        sumsq += t0 * t0 + t1 * t1 + t2 * t2 + t3 * t3;
    }
    sumsq += __shfl_xor(sumsq, 1, 64);
    sumsq += __shfl_xor(sumsq, 2, 64);
    sumsq += __shfl_xor(sumsq, 4, 64);
    sumsq += __shfl_xor(sumsq, 8, 64);
    float inv = 1.f / fmaxf(sqrtf(sumsq), 1e-12f);

    size_t nl = (size_t)n * LL + l;
    unsigned short* dh = VhT + nl * KK + cg * 16;
    unsigned short* dl = VlT + nl * KK + cg * 16;
#pragma unroll
    for (int ci = 0; ci < 4; ++ci) {
        ushort4 hv, lv;
        unsigned short* ph = &hv.x;
        unsigned short* pl = &lv.x;
#pragma unroll
        for (int tp = 0; tp < 4; ++tp) {
            float v = vals[ci * 4 + tp] * inv;
            _Float16 h = (fabsf(v) < 6.1035e-5f) ? (_Float16)0 : (_Float16)v;
            _Float16 lo = (_Float16)((v - (float)h) * 2048.0f);
            ph[tp] = h2u(h * (_Float16)2048.0f);   // exact pow2 scale
            pl[tp] = h2u(lo);
        }
        *(ushort4*)(dh + ci * 4) = hv;
        *(ushort4*)(dl + ci * 4) = lv;
    }
}

// Kernel 2: triangular 128x128-tiled similarity-max via split-fp16 32x32x16 MFMA.
// acc = Vh1'Vh2' + Vh1'Vl2 + Vl1Vh2' = 2^22 * v1.v2 ; val = acc * 2^-22.
// LDS: 4 buffers (Ah|Al|Bh|Bl) of 128 rows x 32 halves, UNPADDED 64B rows with
// XOR chunk swizzle p = c ^ ((row>>1)&3)  -> 32KB total (5 blocks/CU), uniform
// 8-accesses/bank for both ds_write_b128 and ds_read_b128.
// 32x32x16 layouts: A/B row(col)=lane&31, k=(lane>>5)*8+j;
// C/D: col=lane&31, row=(reg&3)+8*(reg>>2)+4*(lane>>5).
__global__ __launch_bounds__(256) void simmax(const unsigned short* __restrict__ Vh,
                                              const unsigned short* __restrict__ Vl,
                                              unsigned long long* __restrict__ best) {
    __shared__ __align__(16) unsigned short S[16384];   // 32 KB

    int bx = blockIdx.x;              // 0..2111
    int xcd = bx & 7, idx = bx >> 3;  // XCD-pin: each XCD owns half of one batch
    int n = xcd >> 1;
    int t = (xcd & 1) * 264 + idx;    // 0..527
    int j = (int)((sqrtf(8.f * (float)t + 1.f) - 1.f) * 0.5f);
    while ((j + 1) * (j + 2) / 2 <= t) ++j;
    while (j * (j + 1) / 2 > t) --j;
    int i = t - j * (j + 1) / 2;
    int l0 = i * 128, m0 = j * 128;

    const unsigned short* VhB = Vh + (size_t)n * (LL * KK);
    const unsigned short* VlB = Vl + (size_t)n * (LL * KK);

    int tid = threadIdx.x;
    int w = tid >> 6, lane = tid & 63;
    int r5 = lane & 31, h5 = lane >> 5;
    int rw = (w & 1) * 64;    // wave rows (l)
    int cw = (w >> 1) * 64;   // wave cols (m)
    bool skip = (i == j) && (rw == 64) && (cw == 0);  // fully l>m

    f32x16 acc[2][2];
#pragma unroll
    for (int r = 0; r < 2; ++r)
#pragma unroll
        for (int c = 0; c < 2; ++c) acc[r][c] = (f32x16)0.f;

    int srow = tid >> 2;          // 0..63
    int scl = tid & 3;            // global chunk 0..3 (8 halves each) - coalesced
    int sp = (scl ^ ((srow >> 1) & 3)) * 8;   // physical chunk offset (halves);
                                              // same for row srow and 64+srow (64>>1 % 4 == 0)
    int shg = scl * 8;            // global offset in halves

    // fragment-row swizzle: ((rw + r*32 + r5)>>1)&3 == (r5>>1)&3  (rw, r*32 vanish mod 4)
    int sfr = (r5 >> 1) & 3;

    for (int k0 = 0; k0 < KK; k0 += 32) {
        const size_t ra = (size_t)(l0 + srow) * KK + k0 + shg;
        const size_t rb = (size_t)(l0 + 64 + srow) * KK + k0 + shg;
        const size_t rc = (size_t)(m0 + srow) * KK + k0 + shg;
        const size_t rd = (size_t)(m0 + 64 + srow) * KK + k0 + shg;
        uint4 ah0 = *(const uint4*)(VhB + ra);
        uint4 ah1 = *(const uint4*)(VhB + rb);
        uint4 al0 = *(const uint4*)(VlB + ra);
        uint4 al1 = *(const uint4*)(VlB + rb);
        uint4 bh0 = *(const uint4*)(VhB + rc);
        uint4 bh1 = *(const uint4*)(VhB + rd);
        uint4 bl0 = *(const uint4*)(VlB + rc);
        uint4 bl1 = *(const uint4*)(VlB + rd);
        __syncthreads();
        *(uint4*)&S[srow * 32 + sp]                 = ah0;   // Ah
        *(uint4*)&S[(64 + srow) * 32 + sp]          = ah1;
        *(uint4*)&S[4096 + srow * 32 + sp]          = al0;   // Al
        *(uint4*)&S[4096 + (64 + srow) * 32 + sp]   = al1;
        *(uint4*)&S[8192 + srow * 32 + sp]          = bh0;   // Bh
        *(uint4*)&S[8192 + (64 + srow) * 32 + sp]   = bh1;
        *(uint4*)&S[12288 + srow * 32 + sp]         = bl0;   // Bl
        *(uint4*)&S[12288 + (64 + srow) * 32 + sp]  = bl1;
        __syncthreads();
        if (!skip) {
            half8 fah[2][2], fal[2][2], fbh[2][2], fbl[2][2];
#pragma unroll
            for (int r = 0; r < 2; ++r)
#pragma unroll
                for (int kc = 0; kc < 2; ++kc) {
                    int pc = ((kc * 2 + h5) ^ sfr) * 8;
                    int ao = (rw + r * 32 + r5) * 32 + pc;
                    int bo = (cw + r * 32 + r5) * 32 + pc;
                    fah[r][kc] = *(half8*)&S[ao];
                    fal[r][kc] = *(half8*)&S[4096 + ao];
                    fbh[r][kc] = *(half8*)&S[8192 + bo];
                    fbl[r][kc] = *(half8*)&S[12288 + bo];
                }
#pragma unroll
            for (int kc = 0; kc < 2; ++kc)
#pragma unroll
                for (int r = 0; r < 2; ++r)
#pragma unroll
                    for (int c = 0; c < 2; ++c)
                        acc[r][c] = __builtin_amdgcn_mfma_f32_32x32x16_f16(fal[r][kc], fbh[c][kc], acc[r][c], 0, 0, 0);
#pragma unroll
            for (int kc = 0; kc < 2; ++kc)
#pragma unroll
                for (int r = 0; r < 2; ++r)
#pragma unroll
                    for (int c = 0; c < 2; ++c)
                        acc[r][c] = __builtin_amdgcn_mfma_f32_32x32x16_f16(fah[r][kc], fbl[c][kc], acc[r][c], 0, 0, 0);
#pragma unroll
            for (int kc = 0; kc < 2; ++kc)
#pragma unroll
                for (int r = 0; r < 2; ++r)
#pragma unroll
                    for (int c = 0; c < 2; ++c)
                        acc[r][c] = __builtin_amdgcn_mfma_f32_32x32x16_f16(fah[r][kc], fbh[c][kc], acc[r][c], 0, 0, 0);
        }
    }

    if (skip) return;
    unsigned long long* bb = best + (size_t)n * LL;
    const float s = 1.f / 4194304.f;   // 2^-22
#pragma unroll
    for (int c = 0; c < 2; ++c) {
        int m = m0 + cw + c * 32 + r5;
        unsigned long long key = 0ull;
#pragma unroll
        for (int r = 0; r < 2; ++r)
#pragma unroll
            for (int g = 0; g < 16; ++g) {
                int l = l0 + rw + r * 32 + (g & 3) + 8 * (g >> 2) + 4 * h5;
                if (l < m) {
                    float v = acc[r][c][g] * s;
                    unsigned long long k2 =
                        ((unsigned long long)f2ord(v) << 32) |
                        (unsigned long long)(0xFFFFFFFFu - (unsigned)l);
                    key = (k2 > key) ? k2 : key;
                }
            }
        unsigned long long o = __shfl_xor(key, 32, 64);
        key = (o > key) ? o : key;
        if (h5 == 0 && key != 0ull) atomicMax(bb + m, key);
    }
}

// Kernel 3: unpack best, write S, U, ref_unfold, arg (float values), m==0 overrides.
// 4096 blocks (16 channel-groups of 4) for TLP; XCD-pinned per batch.
__global__ __launch_bounds__(256) void writeout(const float* __restrict__ yhat,
                                                const float* __restrict__ yprob,
                                                const unsigned long long* __restrict__ best,
                                                float* __restrict__ out) {
    int blk = blockIdx.x;                     // 0..4095
    int xcd = blk & 7;
    int n = xcd >> 1;
    int idx = (blk >> 3) + (xcd & 1) * 512;   // 0..1023
    int mb = idx >> 4;                        // 0..63
    int fc = idx & 15;                        // channel group of 4
    int tid = threadIdx.x;
    int mm = tid & 63;
    int fs = tid >> 6;                        // 0..3
    int c = fc * 4 + fs;
    int m = mb * 64 + mm;

    unsigned long long key = best[(size_t)n * LL + m];
    unsigned l = 0xFFFFFFFFu - (unsigned)(key & 0xFFFFFFFFull);
    float val = ord2f((unsigned)(key >> 32));
    bool zero = (m == 0);
    if (zero) l = 0;
    int ly = (int)(l >> 6), lx = (int)(l & 63);

    float* Sout = out;                       // [4,1,64,64]
    float* Uout = out + 16384;               // [4,1,64,64]
    float* Rout = out + 32768;               // [4,576,4096]
    float* Aout = out + 9469952;             // [4,4096] as float values

    if (fc == 0 && fs == 0) {
        float S = zero ? 1e-8f : fminf(fmaxf(val, 1e-8f), 1.0f);
        float U = zero ? 1e-8f : fminf(fmaxf(yprob[(size_t)n * LL + l], 1e-8f), 1.0f);
        Sout[(size_t)n * LL + m] = S;
        Uout[(size_t)n * LL + m] = U;
        Aout[(size_t)n * LL + m] = zero ? -1.0f : (float)l;
    }

    const float* src = yhat + (size_t)n * (Cc * LL);
    const float* plane = src + (size_t)c * LL;
    float* dst = Rout + (size_t)n * (576 * LL) + m;
    bool fast = (!zero) && (lx >= 1) && (lx <= 61);
#pragma unroll
    for (int r3 = 0; r3 < 3; ++r3) {
        int yy = ly + r3 - 1;
        bool rowok = (!zero) && (yy >= 0) && (yy < 64);
        float t0 = 0.f, t1 = 0.f, t2 = 0.f;
        if (rowok) {
            if (fast) {
                f4a v = *(const f4a*)(plane + yy * 64 + lx - 1);
                t0 = v.x; t1 = v.y; t2 = v.z;
            } else {
                if (lx > 0)  t0 = plane[yy * 64 + lx - 1];
                t1 = plane[yy * 64 + lx];
                if (lx < 63) t2 = plane[yy * 64 + lx + 1];
            }
        }
        size_t f = (size_t)(c * 9 + r3 * 3) * LL;
        __builtin_nontemporal_store(t0, dst + f);
        __builtin_nontemporal_store(t1, dst + f + LL);
        __builtin_nontemporal_store(t2, dst + f + 2 * (size_t)LL);
    }
}

extern "C" void kernel_launch(void* const* d_in, const int* in_sizes, int n_in,
                              void* d_out, int out_size, void* d_ws, size_t ws_size,
                              hipStream_t stream) {
    const float* yhat  = (const float*)d_in[0];
    const float* yprob = (const float*)d_in[1];
    float* out = (float*)d_out;

    unsigned short* VhT = (unsigned short*)d_ws;                       // 8 MiB
    unsigned short* VlT = (unsigned short*)((char*)d_ws + 8388608);    // 8 MiB
    unsigned long long* best =
        (unsigned long long*)((char*)d_ws + 16777216);                 // 128 KiB

    build_v<<<1024, 256, 0, stream>>>(yhat, VhT, VlT, best);
    simmax<<<Nn * TRI2, 256, 0, stream>>>(VhT, VlT, best);
    writeout<<<4096, 256, 0, stream>>>(yhat, yprob, best, out);
}